// Round 1
// baseline (106.867 us; speedup 1.0000x reference)
//
#include <hip/hip_runtime.h>
#include <math.h>

// SSIM loss, fused single-pass tile kernel.
// Tile: 64 cols x 32 rows of output per block, 256 threads.
// Phases: (1) stage zero-padded inputs to LDS (float4), (2) horizontal
// separable conv of 5 quantities (a,b,a2,b2,ab) into LDS h-planes,
// (3) vertical conv + SSIM map + block reduction -> partials in d_ws,
// then a tiny deterministic finalize kernel.

#define TW 64
#define TH 32
#define HR (TH + 10)      // 42 staged rows (5 halo each side)
#define IWP 80            // staged input cols, float4-aligned (c0-8 .. c0+71)
#define IMGH 512
#define IMGW 512
#define C1F 1.0e-4f
#define C2F 9.0e-4f
#define NPIX (16 * 3 * 512 * 512)
#define NBLOCKS (8 * 16 * 48)

struct GaussW { float w[11]; };

__global__ __launch_bounds__(256, 2)
void ssim_tile(const float* __restrict__ img1, const float* __restrict__ img2,
               float* __restrict__ partials, GaussW gw) {
    __shared__ float sA[HR][IWP];
    __shared__ float sB[HR][IWP];
    __shared__ float sH[5][HR][TW];
    __shared__ float wsum[4];

    const int tid = threadIdx.x;
    const int r0 = blockIdx.y * TH;
    const int c0 = blockIdx.x * TW;
    const size_t pbase = (size_t)blockIdx.z * (IMGH * IMGW);
    const float* a0 = img1 + pbase;
    const float* b0 = img2 + pbase;

    // ---- Phase 1: stage inputs with halo, zero-padded, float4 loads ----
    // LDS col j <-> input col (c0 - 8 + j); rows r0-5 .. r0+36.
    for (int idx = tid; idx < HR * (IWP / 4); idx += 256) {
        int row = idx / (IWP / 4);
        int cg  = idx - row * (IWP / 4);
        int gr = r0 - 5 + row;
        int gc = c0 - 8 + cg * 4;
        float4 va = make_float4(0.f, 0.f, 0.f, 0.f);
        float4 vb = va;
        if ((unsigned)gr < IMGH && (unsigned)gc < IMGW) {
            va = *reinterpret_cast<const float4*>(&a0[(size_t)gr * IMGW + gc]);
            vb = *reinterpret_cast<const float4*>(&b0[(size_t)gr * IMGW + gc]);
        }
        *reinterpret_cast<float4*>(&sA[row][cg * 4]) = va;
        *reinterpret_cast<float4*>(&sB[row][cg * 4]) = vb;
    }
    __syncthreads();

    // ---- Phase 2: horizontal pass, 4 output cols per work item ----
    // Output col (c+o): sum_k w[k] * in[c0 + c+o-5+k]  -> LDS local idx o+k+3.
    for (int idx = tid; idx < HR * (TW / 4); idx += 256) {
        int row = idx >> 4;
        int cg  = idx & 15;
        int c = cg * 4;
        float av[20], bv[20];
#pragma unroll
        for (int t = 0; t < 5; ++t) {
            *reinterpret_cast<float4*>(&av[t * 4]) =
                *reinterpret_cast<const float4*>(&sA[row][c + t * 4]);
            *reinterpret_cast<float4*>(&bv[t * 4]) =
                *reinterpret_cast<const float4*>(&sB[row][c + t * 4]);
        }
        float sa[4], sb[4], saa[4], sbb[4], sab[4];
#pragma unroll
        for (int o = 0; o < 4; ++o) { sa[o] = sb[o] = saa[o] = sbb[o] = sab[o] = 0.f; }
#pragma unroll
        for (int j = 0; j < 14; ++j) {
            float a = av[j + 3], b = bv[j + 3];
            float aa = a * a, bb = b * b, ab = a * b;
#pragma unroll
            for (int o = 0; o < 4; ++o) {
                int k = j - o;
                if (k >= 0 && k < 11) {
                    float wk = gw.w[k];
                    sa[o]  += wk * a;  sb[o]  += wk * b;
                    saa[o] += wk * aa; sbb[o] += wk * bb; sab[o] += wk * ab;
                }
            }
        }
        *reinterpret_cast<float4*>(&sH[0][row][c]) = make_float4(sa[0],  sa[1],  sa[2],  sa[3]);
        *reinterpret_cast<float4*>(&sH[1][row][c]) = make_float4(sb[0],  sb[1],  sb[2],  sb[3]);
        *reinterpret_cast<float4*>(&sH[2][row][c]) = make_float4(saa[0], saa[1], saa[2], saa[3]);
        *reinterpret_cast<float4*>(&sH[3][row][c]) = make_float4(sbb[0], sbb[1], sbb[2], sbb[3]);
        *reinterpret_cast<float4*>(&sH[4][row][c]) = make_float4(sab[0], sab[1], sab[2], sab[3]);
    }
    __syncthreads();

    // ---- Phase 3: vertical pass (4 rows x 1 col per item) + SSIM map ----
    float lsum = 0.f;
#pragma unroll
    for (int it = 0; it < 2; ++it) {
        int idx = tid + it * 256;          // 512 items total, all threads active
        int col = idx & 63;
        int rr  = (idx >> 6) * 4;
        float m1[4], m2[4], xaa[4], xbb[4], xab[4];
#pragma unroll
        for (int o = 0; o < 4; ++o) { m1[o] = m2[o] = xaa[o] = xbb[o] = xab[o] = 0.f; }
#pragma unroll
        for (int j = 0; j < 14; ++j) {
            float h0 = sH[0][rr + j][col];
            float h1 = sH[1][rr + j][col];
            float h2 = sH[2][rr + j][col];
            float h3 = sH[3][rr + j][col];
            float h4 = sH[4][rr + j][col];
#pragma unroll
            for (int o = 0; o < 4; ++o) {
                int k = j - o;
                if (k >= 0 && k < 11) {
                    float wk = gw.w[k];
                    m1[o]  += wk * h0; m2[o]  += wk * h1;
                    xaa[o] += wk * h2; xbb[o] += wk * h3; xab[o] += wk * h4;
                }
            }
        }
#pragma unroll
        for (int o = 0; o < 4; ++o) {
            float mu1 = m1[o], mu2 = m2[o];
            float mu11 = mu1 * mu1, mu22 = mu2 * mu2, mu12 = mu1 * mu2;
            float s1  = xaa[o] - mu11;
            float s2  = xbb[o] - mu22;
            float s12 = xab[o] - mu12;
            float num = (2.f * mu12 + C1F) * (2.f * s12 + C2F);
            float den = (mu11 + mu22 + C1F) * (s1 + s2 + C2F);
            lsum += num / den;
        }
    }

    // ---- Deterministic block reduction ----
#pragma unroll
    for (int off = 32; off > 0; off >>= 1) lsum += __shfl_down(lsum, off, 64);
    if ((tid & 63) == 0) wsum[tid >> 6] = lsum;
    __syncthreads();
    if (tid == 0) {
        float t = wsum[0] + wsum[1] + wsum[2] + wsum[3];
        partials[((size_t)blockIdx.z * gridDim.y + blockIdx.y) * gridDim.x + blockIdx.x] = t;
    }
}

__global__ void ssim_reduce(const float* __restrict__ partials, float* __restrict__ out, int n) {
    __shared__ float lds[256];
    float s = 0.f;
    for (int i = threadIdx.x; i < n; i += 256) s += partials[i];
    lds[threadIdx.x] = s;
    __syncthreads();
    for (int off = 128; off > 0; off >>= 1) {
        if ((int)threadIdx.x < off) lds[threadIdx.x] += lds[threadIdx.x + off];
        __syncthreads();
    }
    if (threadIdx.x == 0) out[0] = 1.f - lds[0] / (float)NPIX;
}

extern "C" void kernel_launch(void* const* d_in, const int* in_sizes, int n_in,
                              void* d_out, int out_size, void* d_ws, size_t ws_size,
                              hipStream_t stream) {
    const float* img1 = (const float*)d_in[0];
    const float* img2 = (const float*)d_in[1];
    float* out = (float*)d_out;
    float* partials = (float*)d_ws;

    // Gaussian weights (normalized 1D, sigma=1.5, ws=11) computed on host —
    // deterministic, passed by value.
    GaussW gw;
    double g[11], s = 0.0;
    for (int i = 0; i < 11; ++i) {
        double d = (double)i - 5.0;
        g[i] = exp(-(d * d) / 4.5);
        s += g[i];
    }
    for (int i = 0; i < 11; ++i) gw.w[i] = (float)(g[i] / s);

    dim3 grid(IMGW / TW, IMGH / TH, 48);
    ssim_tile<<<grid, 256, 0, stream>>>(img1, img2, partials, gw);
    ssim_reduce<<<1, 256, 0, stream>>>(partials, out, NBLOCKS);
}

// Round 2
// 100.859 us; speedup vs baseline: 1.0596x; 1.0596x over previous
//
#include <hip/hip_runtime.h>

// SSIM loss — fused tile kernel, round 2.
// Tile 64 cols x 16 rows, 256 threads, 3 blocks/CU (LDS ~49.6 KB).
// Packed-f32 (v_pk_fma_f32) conv accumulation over output pairs.

#define TW 64
#define TH 16
#define HR (TH + 10)      // 26 staged rows (5 halo each side)
#define IWP 80            // staged input cols, float4-aligned
#define TWP2 (TW + 2)     // padded row stride (in float2) for packed h-planes
#define IMGH 512
#define IMGW 512
#define C1F 1.0e-4f
#define C2F 9.0e-4f
#define NPIX (16 * 3 * 512 * 512)
#define GX (IMGW / TW)    // 8
#define GY (IMGH / TH)    // 32
#define GZ 48
#define NBLOCKS (GX * GY * GZ)  // 12288

typedef float v2f __attribute__((ext_vector_type(2)));

// Gaussian weights, sigma=1.5, ws=11 (double-computed, folded to f32).
#define W0 0.0010283818f
#define W1 0.0075987503f
#define W2 0.0360007547f
#define W3 0.1093606960f
#define W4 0.2130055367f
#define W5 0.2660117184f

static __device__ __forceinline__ v2f pfma(v2f a, v2f b, v2f c) {
    return __builtin_elementwise_fma(a, b, c);
}
static __device__ __forceinline__ v2f splat(float x) { v2f r; r.x = x; r.y = x; return r; }

__global__ __launch_bounds__(256, 3)
void ssim_tile(const float* __restrict__ img1, const float* __restrict__ img2,
               float* __restrict__ partials) {
    __shared__ float sA[HR][IWP];
    __shared__ float sB[HR][IWP];
    __shared__ v2f   sP0[HR][TWP2];   // (sa, sb)
    __shared__ v2f   sP1[HR][TWP2];   // (saa, sbb)
    __shared__ float sP2[HR][TW];     // sab
    __shared__ float wsum[4];

    const float W[11] = {W0, W1, W2, W3, W4, W5, W4, W3, W2, W1, W0};
    // Packed weight-pair table: wp[j] = (w[j], w[j-1]) with zeros off-range.
    v2f wp[12];
#pragma unroll
    for (int j = 0; j < 12; ++j) {
        wp[j].x = (j <= 10) ? W[j] : 0.f;
        wp[j].y = (j >= 1) ? W[j - 1] : 0.f;
    }

    const int tid = threadIdx.x;
    const int r0 = blockIdx.y * TH;
    const int c0 = blockIdx.x * TW;
    const size_t pbase = (size_t)blockIdx.z * (IMGH * IMGW);
    const float* a0 = img1 + pbase;
    const float* b0 = img2 + pbase;

    // ---- Phase 1: stage inputs with halo, zero-padded, float4 loads ----
    for (int idx = tid; idx < HR * (IWP / 4); idx += 256) {   // 26*20 = 520
        int row = idx / (IWP / 4);
        int cg  = idx - row * (IWP / 4);
        int gr = r0 - 5 + row;
        int gc = c0 - 8 + cg * 4;
        float4 va = make_float4(0.f, 0.f, 0.f, 0.f);
        float4 vb = va;
        if ((unsigned)gr < IMGH && (unsigned)gc < IMGW) {
            va = *reinterpret_cast<const float4*>(&a0[(size_t)gr * IMGW + gc]);
            vb = *reinterpret_cast<const float4*>(&b0[(size_t)gr * IMGW + gc]);
        }
        *reinterpret_cast<float4*>(&sA[row][cg * 4]) = va;
        *reinterpret_cast<float4*>(&sB[row][cg * 4]) = vb;
    }
    __syncthreads();

    // ---- Phase 2: horizontal conv, 4 output cols/item, packed over col pairs ----
    // Output col (c+o) center at local idx c+o+8; taps j=0..13 read av[j+3].
    for (int idx = tid; idx < HR * (TW / 4); idx += 256) {    // 26*16 = 416
        int row = idx >> 4;
        int c   = (idx & 15) * 4;
        float av[20], bv[20];
#pragma unroll
        for (int t = 0; t < 5; ++t) {
            *reinterpret_cast<float4*>(&av[t * 4]) =
                *reinterpret_cast<const float4*>(&sA[row][c + t * 4]);
            *reinterpret_cast<float4*>(&bv[t * 4]) =
                *reinterpret_cast<const float4*>(&sB[row][c + t * 4]);
        }
        v2f sa01 = 0, sa23 = 0, sb01 = 0, sb23 = 0;
        v2f saa01 = 0, saa23 = 0, sbb01 = 0, sbb23 = 0, sab01 = 0, sab23 = 0;
#pragma unroll
        for (int j = 0; j < 14; ++j) {
            float a = av[j + 3], b = bv[j + 3];
            v2f av2 = splat(a), bv2 = splat(b);
            v2f aa = splat(a * a), bb = splat(b * b), ab = splat(a * b);
            if (j <= 11) {
                v2f w = wp[j];
                sa01  = pfma(w, av2, sa01);  sb01  = pfma(w, bv2, sb01);
                saa01 = pfma(w, aa, saa01);  sbb01 = pfma(w, bb, sbb01);
                sab01 = pfma(w, ab, sab01);
            }
            if (j >= 2) {
                v2f w = wp[j - 2];
                sa23  = pfma(w, av2, sa23);  sb23  = pfma(w, bv2, sb23);
                saa23 = pfma(w, aa, saa23);  sbb23 = pfma(w, bb, sbb23);
                sab23 = pfma(w, ab, sab23);
            }
        }
        v2f p00; p00.x = sa01.x;  p00.y = sb01.x;
        v2f p01; p01.x = sa01.y;  p01.y = sb01.y;
        v2f p02; p02.x = sa23.x;  p02.y = sb23.x;
        v2f p03; p03.x = sa23.y;  p03.y = sb23.y;
        sP0[row][c + 0] = p00; sP0[row][c + 1] = p01;
        sP0[row][c + 2] = p02; sP0[row][c + 3] = p03;
        v2f q00; q00.x = saa01.x; q00.y = sbb01.x;
        v2f q01; q01.x = saa01.y; q01.y = sbb01.y;
        v2f q02; q02.x = saa23.x; q02.y = sbb23.x;
        v2f q03; q03.x = saa23.y; q03.y = sbb23.y;
        sP1[row][c + 0] = q00; sP1[row][c + 1] = q01;
        sP1[row][c + 2] = q02; sP1[row][c + 3] = q03;
        *reinterpret_cast<float4*>(&sP2[row][c]) =
            make_float4(sab01.x, sab01.y, sab23.x, sab23.y);
    }
    __syncthreads();

    // ---- Phase 3: vertical conv (4 rows x 1 col per thread, packed row pairs) ----
    const int col = tid & 63;
    const int rr  = (tid >> 6) * 4;   // 0,4,8,12
    v2f m1_01 = 0, m1_23 = 0, m2_01 = 0, m2_23 = 0;
    v2f xa_01 = 0, xa_23 = 0, xb_01 = 0, xb_23 = 0, xc_01 = 0, xc_23 = 0;
#pragma unroll
    for (int j = 0; j < 14; ++j) {
        v2f h01 = sP0[rr + j][col];
        v2f h23 = sP1[rr + j][col];
        float h4 = sP2[rr + j][col];
        v2f ha = splat(h01.x), hb = splat(h01.y);
        v2f haa = splat(h23.x), hbb = splat(h23.y), hab = splat(h4);
        if (j <= 11) {
            v2f w = wp[j];
            m1_01 = pfma(w, ha, m1_01);  m2_01 = pfma(w, hb, m2_01);
            xa_01 = pfma(w, haa, xa_01); xb_01 = pfma(w, hbb, xb_01);
            xc_01 = pfma(w, hab, xc_01);
        }
        if (j >= 2) {
            v2f w = wp[j - 2];
            m1_23 = pfma(w, ha, m1_23);  m2_23 = pfma(w, hb, m2_23);
            xa_23 = pfma(w, haa, xa_23); xb_23 = pfma(w, hbb, xb_23);
            xc_23 = pfma(w, hab, xc_23);
        }
    }
    float mu1v[4] = {m1_01.x, m1_01.y, m1_23.x, m1_23.y};
    float mu2v[4] = {m2_01.x, m2_01.y, m2_23.x, m2_23.y};
    float xaav[4] = {xa_01.x, xa_01.y, xa_23.x, xa_23.y};
    float xbbv[4] = {xb_01.x, xb_01.y, xb_23.x, xb_23.y};
    float xabv[4] = {xc_01.x, xc_01.y, xc_23.x, xc_23.y};
    float lsum = 0.f;
#pragma unroll
    for (int o = 0; o < 4; ++o) {
        float mu1 = mu1v[o], mu2 = mu2v[o];
        float mu11 = mu1 * mu1, mu22 = mu2 * mu2, mu12 = mu1 * mu2;
        float s1  = xaav[o] - mu11;
        float s2  = xbbv[o] - mu22;
        float s12 = xabv[o] - mu12;
        float num = (2.f * mu12 + C1F) * (2.f * s12 + C2F);
        float den = (mu11 + mu22 + C1F) * (s1 + s2 + C2F);
        lsum += num * __builtin_amdgcn_rcpf(den);
    }

    // ---- Deterministic block reduction ----
#pragma unroll
    for (int off = 32; off > 0; off >>= 1) lsum += __shfl_down(lsum, off, 64);
    if ((tid & 63) == 0) wsum[tid >> 6] = lsum;
    __syncthreads();
    if (tid == 0) {
        float t = wsum[0] + wsum[1] + wsum[2] + wsum[3];
        partials[((size_t)blockIdx.z * GY + blockIdx.y) * GX + blockIdx.x] = t;
    }
}

__global__ void ssim_reduce(const float* __restrict__ partials, float* __restrict__ out, int n) {
    __shared__ float lds[256];
    float s = 0.f;
    for (int i = threadIdx.x; i < n; i += 256) s += partials[i];
    lds[threadIdx.x] = s;
    __syncthreads();
    for (int off = 128; off > 0; off >>= 1) {
        if ((int)threadIdx.x < off) lds[threadIdx.x] += lds[threadIdx.x + off];
        __syncthreads();
    }
    if (threadIdx.x == 0) out[0] = 1.f - lds[0] / (float)NPIX;
}

extern "C" void kernel_launch(void* const* d_in, const int* in_sizes, int n_in,
                              void* d_out, int out_size, void* d_ws, size_t ws_size,
                              hipStream_t stream) {
    const float* img1 = (const float*)d_in[0];
    const float* img2 = (const float*)d_in[1];
    float* out = (float*)d_out;
    float* partials = (float*)d_ws;

    dim3 grid(GX, GY, GZ);
    ssim_tile<<<grid, 256, 0, stream>>>(img1, img2, partials);
    ssim_reduce<<<1, 256, 0, stream>>>(partials, out, NBLOCKS);
}

// Round 3
// 97.246 us; speedup vs baseline: 1.0989x; 1.0372x over previous
//
#include <hip/hip_runtime.h>
#include <hip/hip_fp16.h>

// SSIM loss — round 3.
// Tile 64 cols x 32 rows, 256 threads, 2 blocks/CU (LDS ~79.9 KB).
// P1: stage (a,b)-interleaved inputs (group-of-8 + pad layout).
// P2: horizontal conv, 8 out cols/item, quantity-packed pk_fma; second
//     moments stored as f16 (RNE), (sa,sb) as f32 pairs.
// P3: vertical conv, 1 col x 8 rows/thread, row-pair pk_fma, static LDS
//     offsets; SSIM map + deterministic reduction.

#define IMGH 512
#define IMGW 512
#define TW 64
#define TH 32
#define HRR 42            // TH + 10 staged h-rows
#define C1F 1.0e-4f
#define C2F 9.0e-4f
#define GX 8
#define GY 16
#define GZ 48
#define NBLOCKS (GX * GY * GZ)   // 6144
#define NPIX (16 * 3 * 512 * 512)

typedef float v2f __attribute__((ext_vector_type(2)));

// Gaussian weights, sigma=1.5, ws=11 (validated in r1/r2, absmax 0.0).
#define W0 0.0010283818f
#define W1 0.0075987503f
#define W2 0.0360007547f
#define W3 0.1093606960f
#define W4 0.2130055367f
#define W5 0.2660117184f

static __device__ __forceinline__ v2f pfma(v2f a, v2f b, v2f c) {
    return __builtin_elementwise_fma(a, b, c);
}
static __device__ __forceinline__ v2f splat(float x) { v2f r; r.x = x; r.y = x; return r; }

__global__ __launch_bounds__(256, 2)
void ssim_tile(const float* __restrict__ img1, const float* __restrict__ img2,
               float* __restrict__ partials) {
    // Input pairs (a,b) per col; 80 cols in 10 groups of 8 + 1 v2f pad each.
    __shared__ v2f  sAB[HRR][90];    // 30,240 B ; col c -> idx 9*(c>>3)+(c&7)
    // H-plane (sa,sb) f32 pairs; col c -> idx 6*(c>>2)+(c&3)  (48B quads)
    __shared__ v2f  sPab[HRR][98];   // 32,928 B
    // H-plane (saa,sbb) as half2 per col.
    __shared__ unsigned int sPq[HRR][66];   // 11,088 B
    // H-plane ab as f16, packed 2 cols per uint.
    __shared__ unsigned int sPc[HRR][34];   //  5,712 B
    __shared__ float wsum[4];

    const float W[11] = {W0, W1, W2, W3, W4, W5, W4, W3, W2, W1, W0};
    v2f wp[12];   // wp[i] = (W[i], W[i-1]), zero off-range
#pragma unroll
    for (int i = 0; i < 12; ++i) {
        wp[i].x = (i <= 10) ? W[i] : 0.f;
        wp[i].y = (i >= 1) ? W[i - 1] : 0.f;
    }

    const int tid = threadIdx.x;
    const int r0 = blockIdx.y * TH;
    const int c0 = blockIdx.x * TW;
    const size_t pbase = (size_t)blockIdx.z * (IMGH * IMGW);
    const float* a0 = img1 + pbase;
    const float* b0 = img2 + pbase;

    // ---- Phase 1: stage interleaved inputs (zero-padded halo) ----
    // 840 items: 42 rows x 20 col-quads. LDS col j <-> image col c0-8+j.
    for (int idx = tid; idx < HRR * 20; idx += 256) {
        int row = (unsigned)idx / 20u;
        int t   = idx - row * 20;          // col-quad: cols 4t..4t+3
        int gr = r0 - 5 + row;
        int gc = c0 - 8 + 4 * t;
        float4 va = make_float4(0.f, 0.f, 0.f, 0.f);
        float4 vb = va;
        if ((unsigned)gr < IMGH && (unsigned)gc < IMGW) {
            va = *reinterpret_cast<const float4*>(&a0[(size_t)gr * IMGW + gc]);
            vb = *reinterpret_cast<const float4*>(&b0[(size_t)gr * IMGW + gc]);
        }
        // cols 4t..4t+3 live in group t>>1, halves by t&1.
        v2f* dst = &sAB[row][9 * (t >> 1) + 4 * (t & 1)];
        *reinterpret_cast<float4*>(&dst[0]) = make_float4(va.x, vb.x, va.y, vb.y);
        *reinterpret_cast<float4*>(&dst[2]) = make_float4(va.z, vb.z, va.w, vb.w);
    }
    __syncthreads();

    // ---- Phase 2: horizontal conv, 8 out cols per item ----
    // 336 items: 42 rows x 8 col-groups. Out col (8cg+m) taps LDS cols
    // 8cg+m+3 .. 8cg+m+13  -> local L = m+3..m+13 within A[0..23].
    auto h_item = [&](int idx) {
        int row = idx >> 3;
        int cg  = idx & 7;
        v2f A[24];
#pragma unroll
        for (int g = 0; g < 3; ++g) {
            int base = 9 * (cg + g);
#pragma unroll
            for (int t = 0; t < 4; ++t) {
                float4 f = *reinterpret_cast<const float4*>(&sAB[row][base + 2 * t]);
                v2f lo; lo.x = f.x; lo.y = f.y;
                v2f hi; hi.x = f.z; hi.y = f.w;
                A[g * 8 + 2 * t]     = lo;
                A[g * 8 + 2 * t + 1] = hi;
            }
        }
        v2f Q[18];  float Pab[18];
#pragma unroll
        for (int d = 3; d <= 20; ++d) {
            Q[d - 3]   = A[d] * A[d];          // (aa, bb)
            Pab[d - 3] = A[d].x * A[d].y;      // ab
        }
        v2f accAB[8], accQ[8], accC[4];
#pragma unroll
        for (int m = 0; m < 8; ++m) { accAB[m] = 0; accQ[m] = 0; }
#pragma unroll
        for (int p = 0; p < 4; ++p) accC[p] = 0;
#pragma unroll
        for (int m = 0; m < 8; ++m) {
#pragma unroll
            for (int k = 0; k <= 10; ++k) {
                int d = m + 3 + k;
                accAB[m] = pfma(splat(W[k]), A[d], accAB[m]);
                accQ[m]  = pfma(splat(W[k]), Q[d - 3], accQ[m]);
            }
        }
#pragma unroll
        for (int p = 0; p < 4; ++p) {
#pragma unroll
            for (int i = 0; i <= 11; ++i) {
                int d = 2 * p + 3 + i;         // local col; out pair (2p,2p+1)
                accC[p] = pfma(wp[i], splat(Pab[d - 3]), accC[p]);
            }
        }
        // stores: (sa,sb) f32 pairs; (saa,sbb) half2; ab f16 col-pairs
        int qb = 12 * cg;                       // v2f idx of quad 2cg
#pragma unroll
        for (int m = 0; m < 8; ++m) {
            sPab[row][qb + 6 * (m >> 2) + (m & 3)] = accAB[m];
            __half2 hq = __half2(__float2half(accQ[m].x), __float2half(accQ[m].y));
            sPq[row][8 * cg + m] = *reinterpret_cast<const unsigned int*>(&hq);
        }
#pragma unroll
        for (int p = 0; p < 4; ++p) {
            __half2 hc = __half2(__float2half(accC[p].x), __float2half(accC[p].y));
            sPc[row][4 * cg + p] = *reinterpret_cast<const unsigned int*>(&hc);
        }
    };
    {
        int idx = tid;           h_item(idx);
        idx = tid + 256;         if (idx < HRR * 8) h_item(idx);
    }
    __syncthreads();

    // ---- Phase 3: vertical conv, 1 col x 8 rows per thread ----
    const int col = tid & 63;
    const int rg  = tid >> 6;
    const int rbase = rg * 8;    // out rows rbase..rbase+7; h-rows rbase+0..17
    const v2f* pab = &sPab[rbase][6 * (col >> 2) + (col & 3)];
    const unsigned int* pq = &sPq[rbase][col];
    const unsigned short* pc =
        reinterpret_cast<const unsigned short*>(&sPc[rbase][0]) + col;

    v2f mA[4], mB[4], mAA[4], mBB[4], mAB[4];
#pragma unroll
    for (int o = 0; o < 4; ++o) { mA[o]=0; mB[o]=0; mAA[o]=0; mBB[o]=0; mAB[o]=0; }
#pragma unroll
    for (int j = 0; j < 18; ++j) {
        v2f hab = pab[j * 98];
        unsigned int q = pq[j * 66];
        unsigned short cb = pc[j * 68];
        float2 qf = __half22float2(*reinterpret_cast<const __half2*>(&q));
        float hcc = __half2float(__ushort_as_half(cb));
#pragma unroll
        for (int o = 0; o < 4; ++o) {
            int i = j - 2 * o;                 // wp index; acc rows (2o,2o+1)
            if (i >= 0 && i <= 11) {
                mA[o]  = pfma(wp[i], splat(hab.x), mA[o]);
                mB[o]  = pfma(wp[i], splat(hab.y), mB[o]);
                mAA[o] = pfma(wp[i], splat(qf.x), mAA[o]);
                mBB[o] = pfma(wp[i], splat(qf.y), mBB[o]);
                mAB[o] = pfma(wp[i], splat(hcc), mAB[o]);
            }
        }
    }

    float lsum = 0.f;
#pragma unroll
    for (int o = 0; o < 4; ++o) {
        v2f mu1 = mA[o], mu2 = mB[o];
        v2f mu11 = mu1 * mu1, mu22 = mu2 * mu2, mu12 = mu1 * mu2;
        v2f s1  = mAA[o] - mu11;
        v2f s2  = mBB[o] - mu22;
        v2f s12 = mAB[o] - mu12;
        v2f num = (2.f * mu12 + C1F) * (2.f * s12 + C2F);
        v2f den = (mu11 + mu22 + C1F) * (s1 + s2 + C2F);
        lsum += num.x * __builtin_amdgcn_rcpf(den.x);
        lsum += num.y * __builtin_amdgcn_rcpf(den.y);
    }

    // ---- Deterministic block reduction ----
#pragma unroll
    for (int off = 32; off > 0; off >>= 1) lsum += __shfl_down(lsum, off, 64);
    if ((tid & 63) == 0) wsum[tid >> 6] = lsum;
    __syncthreads();
    if (tid == 0) {
        float t = wsum[0] + wsum[1] + wsum[2] + wsum[3];
        partials[((size_t)blockIdx.z * GY + blockIdx.y) * GX + blockIdx.x] = t;
    }
}

__global__ void ssim_reduce(const float* __restrict__ partials, float* __restrict__ out, int n) {
    __shared__ float lds[256];
    float s = 0.f;
    for (int i = threadIdx.x; i < n; i += 256) s += partials[i];
    lds[threadIdx.x] = s;
    __syncthreads();
    for (int off = 128; off > 0; off >>= 1) {
        if ((int)threadIdx.x < off) lds[threadIdx.x] += lds[threadIdx.x + off];
        __syncthreads();
    }
    if (threadIdx.x == 0) out[0] = 1.f - lds[0] / (float)NPIX;
}

extern "C" void kernel_launch(void* const* d_in, const int* in_sizes, int n_in,
                              void* d_out, int out_size, void* d_ws, size_t ws_size,
                              hipStream_t stream) {
    const float* img1 = (const float*)d_in[0];
    const float* img2 = (const float*)d_in[1];
    float* out = (float*)d_out;
    float* partials = (float*)d_ws;

    dim3 grid(GX, GY, GZ);
    ssim_tile<<<grid, 256, 0, stream>>>(img1, img2, partials);
    ssim_reduce<<<1, 256, 0, stream>>>(partials, out, NBLOCKS);
}

// Round 4
// 86.214 us; speedup vs baseline: 1.2396x; 1.1280x over previous
//
#include <hip/hip_runtime.h>
#include <hip/hip_fp16.h>

// SSIM loss — round 4: occupancy push.
// Tile 64 cols x 16 rows, 256 threads, LDS ~36 KB -> 4 blocks/CU.
// P1: stage (a,b)-interleaved f32 inputs. P2: horizontal conv (8 cols/item,
// quantity-packed pk_fma), ALL h-planes stored f16 (RNE). P3: vertical conv
// 1 col x 4 rows/thread, row-pair pk_fma, static offsets; SSIM + reduction.

#define IMGH 512
#define IMGW 512
#define TW 64
#define TH 16
#define HRR 26            // TH + 10 staged h-rows
#define C1F 1.0e-4f
#define C2F 9.0e-4f
#define GX 8
#define GY 32
#define GZ 48
#define NBLOCKS (GX * GY * GZ)   // 12288
#define NPIX (16 * 3 * 512 * 512)

typedef float v2f __attribute__((ext_vector_type(2)));

// Gaussian weights, sigma=1.5, ws=11 (validated r1-r3, absmax 0.0).
#define W0 0.0010283818f
#define W1 0.0075987503f
#define W2 0.0360007547f
#define W3 0.1093606960f
#define W4 0.2130055367f
#define W5 0.2660117184f

static __device__ __forceinline__ v2f pfma(v2f a, v2f b, v2f c) {
    return __builtin_elementwise_fma(a, b, c);
}
static __device__ __forceinline__ v2f splat(float x) { v2f r; r.x = x; r.y = x; return r; }

__global__ __launch_bounds__(256, 4)
void ssim_tile(const float* __restrict__ img1, const float* __restrict__ img2,
               float* __restrict__ partials) {
    // Input pairs (a,b) per col; 80 cols in 10 groups of 8 + 1 v2f pad.
    __shared__ v2f sAB[HRR][90];            // 18,720 B ; col c -> 9*(c>>3)+(c&7)
    // H-planes, all f16. Odd uint strides (67/35) -> 2-way max bank aliasing.
    __shared__ unsigned int sPab[HRR][67];  // (sa,sb) half2 per col ; 6,968 B
    __shared__ unsigned int sPq [HRR][67];  // (saa,sbb) half2       ; 6,968 B
    __shared__ unsigned int sPc [HRR][35];  // ab f16, 2 cols/uint   ; 3,640 B
    __shared__ float wsum[4];

    const float W[11] = {W0, W1, W2, W3, W4, W5, W4, W3, W2, W1, W0};
    v2f wp[12];   // wp[i] = (W[i], W[i-1]), zero off-range
#pragma unroll
    for (int i = 0; i < 12; ++i) {
        wp[i].x = (i <= 10) ? W[i] : 0.f;
        wp[i].y = (i >= 1) ? W[i - 1] : 0.f;
    }

    const int tid = threadIdx.x;
    const int r0 = blockIdx.y * TH;
    const int c0 = blockIdx.x * TW;
    const size_t pbase = (size_t)blockIdx.z * (IMGH * IMGW);
    const float* a0 = img1 + pbase;
    const float* b0 = img2 + pbase;

    // ---- Phase 1: stage interleaved inputs (zero-padded halo) ----
    // 520 items: 26 rows x 20 col-quads. LDS col j <-> image col c0-8+j.
    for (int idx = tid; idx < HRR * 20; idx += 256) {
        int row = (unsigned)idx / 20u;
        int t   = idx - row * 20;
        int gr = r0 - 5 + row;
        int gc = c0 - 8 + 4 * t;
        float4 va = make_float4(0.f, 0.f, 0.f, 0.f);
        float4 vb = va;
        if ((unsigned)gr < IMGH && (unsigned)gc < IMGW) {
            va = *reinterpret_cast<const float4*>(&a0[(size_t)gr * IMGW + gc]);
            vb = *reinterpret_cast<const float4*>(&b0[(size_t)gr * IMGW + gc]);
        }
        v2f* dst = &sAB[row][9 * (t >> 1) + 4 * (t & 1)];
        *reinterpret_cast<float4*>(&dst[0]) = make_float4(va.x, vb.x, va.y, vb.y);
        *reinterpret_cast<float4*>(&dst[2]) = make_float4(va.z, vb.z, va.w, vb.w);
    }
    __syncthreads();

    // ---- Phase 2: horizontal conv, 8 out cols per item, 208 items ----
    if (tid < HRR * 8) {
        int row = tid >> 3;
        int cg  = tid & 7;
        v2f A[24];
#pragma unroll
        for (int g = 0; g < 3; ++g) {
            int base = 9 * (cg + g);
#pragma unroll
            for (int t = 0; t < 4; ++t) {
                float4 f = *reinterpret_cast<const float4*>(&sAB[row][base + 2 * t]);
                v2f lo; lo.x = f.x; lo.y = f.y;
                v2f hi; hi.x = f.z; hi.y = f.w;
                A[g * 8 + 2 * t]     = lo;
                A[g * 8 + 2 * t + 1] = hi;
            }
        }
        v2f Q[18];  float Pab[18];
#pragma unroll
        for (int d = 3; d <= 20; ++d) {
            Q[d - 3]   = A[d] * A[d];
            Pab[d - 3] = A[d].x * A[d].y;
        }
        v2f accAB[8], accQ[8], accC[4];
#pragma unroll
        for (int m = 0; m < 8; ++m) { accAB[m] = 0; accQ[m] = 0; }
#pragma unroll
        for (int p = 0; p < 4; ++p) accC[p] = 0;
#pragma unroll
        for (int m = 0; m < 8; ++m) {
#pragma unroll
            for (int k = 0; k <= 10; ++k) {
                int d = m + 3 + k;
                accAB[m] = pfma(splat(W[k]), A[d], accAB[m]);
                accQ[m]  = pfma(splat(W[k]), Q[d - 3], accQ[m]);
            }
        }
#pragma unroll
        for (int p = 0; p < 4; ++p) {
#pragma unroll
            for (int i = 0; i <= 11; ++i) {
                accC[p] = pfma(wp[i], splat(Pab[2 * p + i]), accC[p]);
            }
        }
#pragma unroll
        for (int m = 0; m < 8; ++m) {
            __half2 hab = __half2(__float2half(accAB[m].x), __float2half(accAB[m].y));
            __half2 hq  = __half2(__float2half(accQ[m].x),  __float2half(accQ[m].y));
            sPab[row][8 * cg + m] = *reinterpret_cast<const unsigned int*>(&hab);
            sPq [row][8 * cg + m] = *reinterpret_cast<const unsigned int*>(&hq);
        }
#pragma unroll
        for (int p = 0; p < 4; ++p) {
            __half2 hc = __half2(__float2half(accC[p].x), __float2half(accC[p].y));
            sPc[row][4 * cg + p] = *reinterpret_cast<const unsigned int*>(&hc);
        }
    }
    __syncthreads();

    // ---- Phase 3: vertical conv, 1 col x 4 rows per thread ----
    const int col = tid & 63;
    const int rbase = (tid >> 6) * 4;      // out rows rbase..rbase+3
    const unsigned int* pab = &sPab[rbase][col];
    const unsigned int* pq  = &sPq [rbase][col];
    const unsigned short* pc =
        reinterpret_cast<const unsigned short*>(&sPc[rbase][0]) + col;

    v2f mA[2], mB[2], mAA[2], mBB[2], mAB[2];
#pragma unroll
    for (int o = 0; o < 2; ++o) { mA[o]=0; mB[o]=0; mAA[o]=0; mBB[o]=0; mAB[o]=0; }
#pragma unroll
    for (int j = 0; j < 14; ++j) {
        unsigned int uab = pab[j * 67];
        unsigned int uq  = pq [j * 67];
        unsigned short uc = pc[j * 70];
        float2 abf = __half22float2(*reinterpret_cast<const __half2*>(&uab));
        float2 qf  = __half22float2(*reinterpret_cast<const __half2*>(&uq));
        float  cf  = __half2float(__ushort_as_half(uc));
#pragma unroll
        for (int o = 0; o < 2; ++o) {
            int i = j - 2 * o;
            if (i >= 0 && i <= 11) {
                mA[o]  = pfma(wp[i], splat(abf.x), mA[o]);
                mB[o]  = pfma(wp[i], splat(abf.y), mB[o]);
                mAA[o] = pfma(wp[i], splat(qf.x),  mAA[o]);
                mBB[o] = pfma(wp[i], splat(qf.y),  mBB[o]);
                mAB[o] = pfma(wp[i], splat(cf),    mAB[o]);
            }
        }
    }

    float lsum = 0.f;
#pragma unroll
    for (int o = 0; o < 2; ++o) {
        v2f mu1 = mA[o], mu2 = mB[o];
        v2f mu11 = mu1 * mu1, mu22 = mu2 * mu2, mu12 = mu1 * mu2;
        v2f s1  = mAA[o] - mu11;
        v2f s2  = mBB[o] - mu22;
        v2f s12 = mAB[o] - mu12;
        v2f num = (2.f * mu12 + C1F) * (2.f * s12 + C2F);
        v2f den = (mu11 + mu22 + C1F) * (s1 + s2 + C2F);
        lsum += num.x * __builtin_amdgcn_rcpf(den.x);
        lsum += num.y * __builtin_amdgcn_rcpf(den.y);
    }

    // ---- Deterministic block reduction ----
#pragma unroll
    for (int off = 32; off > 0; off >>= 1) lsum += __shfl_down(lsum, off, 64);
    if ((tid & 63) == 0) wsum[tid >> 6] = lsum;
    __syncthreads();
    if (tid == 0) {
        float t = wsum[0] + wsum[1] + wsum[2] + wsum[3];
        partials[((size_t)blockIdx.z * GY + blockIdx.y) * GX + blockIdx.x] = t;
    }
}

__global__ __launch_bounds__(1024)
void ssim_reduce(const float* __restrict__ partials, float* __restrict__ out, int n) {
    __shared__ float lds[1024];
    float s = 0.f;
    for (int i = threadIdx.x; i < n; i += 1024) s += partials[i];
    lds[threadIdx.x] = s;
    __syncthreads();
    for (int off = 512; off > 0; off >>= 1) {
        if ((int)threadIdx.x < off) lds[threadIdx.x] += lds[threadIdx.x + off];
        __syncthreads();
    }
    if (threadIdx.x == 0) out[0] = 1.f - lds[0] / (float)NPIX;
}

extern "C" void kernel_launch(void* const* d_in, const int* in_sizes, int n_in,
                              void* d_out, int out_size, void* d_ws, size_t ws_size,
                              hipStream_t stream) {
    const float* img1 = (const float*)d_in[0];
    const float* img2 = (const float*)d_in[1];
    float* out = (float*)d_out;
    float* partials = (float*)d_ws;

    dim3 grid(GX, GY, GZ);
    ssim_tile<<<grid, 256, 0, stream>>>(img1, img2, partials);
    ssim_reduce<<<1, 1024, 0, stream>>>(partials, out, NBLOCKS);
}

// Round 5
// 66.879 us; speedup vs baseline: 1.5979x; 1.2891x over previous
//
#include <hip/hip_runtime.h>
#include <hip/hip_fp16.h>

// SSIM loss — round 5: drop input staging (global direct, L2/L3-resident),
// all-f16 packed conv math (v_pk_fma_f16), LDS 17.6KB -> 8 blocks/CU.
// Tile 64x16, 256 threads.
// P2: horizontal conv, 8 out cols/item, direct global reads, f16 core,
//     h-planes stored f16 (no convert at store).
// P3: vertical conv 1 col x 4 rows/thread, f16 accumulation, f32 SSIM map.

#define IMGH 512
#define IMGW 512
#define TW 64
#define TH 16
#define HRR 26            // TH + 10 h-rows
#define C1F 1.0e-4f
#define C2F 9.0e-4f
#define GX 8
#define GY 32
#define GZ 48
#define NBLOCKS (GX * GY * GZ)   // 12288
#define NPIX (16 * 3 * 512 * 512)

// Gaussian weights, sigma=1.5, ws=11 (validated r1-r4).
#define W0 0.0010283818f
#define W1 0.0075987503f
#define W2 0.0360007547f
#define W3 0.1093606960f
#define W4 0.2130055367f
#define W5 0.2660117184f

__global__ __launch_bounds__(256, 8)
void ssim_tile(const float* __restrict__ img1, const float* __restrict__ img2,
               float* __restrict__ partials) {
    // H-planes, all f16. Odd uint strides -> <=2-way bank aliasing (free).
    __shared__ unsigned int sPab[HRR][67];  // (sa,sb) half2   ; 6,968 B
    __shared__ unsigned int sPq [HRR][67];  // (saa,sbb) half2 ; 6,968 B
    __shared__ unsigned int sPc [HRR][35];  // ab f16 x2 cols  ; 3,640 B
    __shared__ float wsum[4];

    const float W[11] = {W0, W1, W2, W3, W4, W5, W4, W3, W2, W1, W0};
    const __half hz = __float2half(0.f);
    __half hWh[11];
#pragma unroll
    for (int i = 0; i < 11; ++i) hWh[i] = __float2half(W[i]);
    __half2 wsH[11];      // (W[i], W[i])
#pragma unroll
    for (int i = 0; i < 11; ++i) wsH[i] = __half2half2(hWh[i]);
    __half2 wpH[12];      // (W[i], W[i-1]), zero off-range
#pragma unroll
    for (int i = 0; i < 12; ++i)
        wpH[i] = __halves2half2(i <= 10 ? hWh[i] : hz, i >= 1 ? hWh[i - 1] : hz);

    const int tid = threadIdx.x;
    const int r0 = blockIdx.y * TH;
    const int c0 = blockIdx.x * TW;
    const size_t pbase = (size_t)blockIdx.z * (IMGH * IMGW);
    const float* a0 = img1 + pbase;
    const float* b0 = img2 + pbase;

    // ---- Phase 2: horizontal conv, 8 out cols per item, 208 items ----
    if (tid < HRR * 8) {
        const int row = tid >> 3;
        const int cg  = tid & 7;
        const int gr  = r0 - 5 + row;
        const bool rowok = (unsigned)gr < IMGH;
        const int grc = rowok ? gr : 0;
        const int gc0 = c0 + 8 * cg - 8;       // local col d <-> global gc0+d
        const float* ra = a0 + (size_t)grc * IMGW;
        const float* rb = b0 + (size_t)grc * IMGW;

        // Build AB[t] = (a,b) f16 for t = d-3, d = 3..20 (cols gc0+3..gc0+20).
        __half2 AB[18];
        {
            float4 va, vb;
            auto ldp = [&](int g) {
                va = make_float4(0.f, 0.f, 0.f, 0.f); vb = va;
                int gc = gc0 + 4 * g;
                if (rowok && (unsigned)gc < IMGW) {
                    va = *reinterpret_cast<const float4*>(ra + gc);
                    vb = *reinterpret_cast<const float4*>(rb + gc);
                }
            };
            ldp(0); AB[0] = __floats2half2_rn(va.w, vb.w);
            ldp(1); AB[1] = __floats2half2_rn(va.x, vb.x);
                    AB[2] = __floats2half2_rn(va.y, vb.y);
                    AB[3] = __floats2half2_rn(va.z, vb.z);
                    AB[4] = __floats2half2_rn(va.w, vb.w);
            ldp(2); AB[5] = __floats2half2_rn(va.x, vb.x);
                    AB[6] = __floats2half2_rn(va.y, vb.y);
                    AB[7] = __floats2half2_rn(va.z, vb.z);
                    AB[8] = __floats2half2_rn(va.w, vb.w);
            ldp(3); AB[9]  = __floats2half2_rn(va.x, vb.x);
                    AB[10] = __floats2half2_rn(va.y, vb.y);
                    AB[11] = __floats2half2_rn(va.z, vb.z);
                    AB[12] = __floats2half2_rn(va.w, vb.w);
            ldp(4); AB[13] = __floats2half2_rn(va.x, vb.x);
                    AB[14] = __floats2half2_rn(va.y, vb.y);
                    AB[15] = __floats2half2_rn(va.z, vb.z);
                    AB[16] = __floats2half2_rn(va.w, vb.w);
            ldp(5); AB[17] = __floats2half2_rn(va.x, vb.x);
        }

        __half2 accAB[8], accQ[8], accC[4];
        const __half2 z2 = __half2half2(hz);
#pragma unroll
        for (int m = 0; m < 8; ++m) { accAB[m] = z2; accQ[m] = z2; }
#pragma unroll
        for (int p = 0; p < 4; ++p) accC[p] = z2;

        // Streaming t-order accumulation: out col (8cg+m) tap k reads t=m+k.
#pragma unroll
        for (int t = 0; t < 18; ++t) {
            __half2 ab = AB[t];
            __half2 q  = __hmul2(ab, ab);                       // (aa,bb)
            __half2 cs = __half2half2(__hmul(__low2half(ab), __high2half(ab)));
#pragma unroll
            for (int m = 0; m < 8; ++m) {
                int k = t - m;
                if (k >= 0 && k <= 10) {
                    accAB[m] = __hfma2(wsH[k], ab, accAB[m]);
                    accQ[m]  = __hfma2(wsH[k], q,  accQ[m]);
                }
            }
#pragma unroll
            for (int p = 0; p < 4; ++p) {
                int i = t - 2 * p;                              // cols (2p,2p+1)
                if (i >= 0 && i <= 11) accC[p] = __hfma2(wpH[i], cs, accC[p]);
            }
        }
#pragma unroll
        for (int m = 0; m < 8; ++m) {
            sPab[row][8 * cg + m] = *reinterpret_cast<const unsigned int*>(&accAB[m]);
            sPq [row][8 * cg + m] = *reinterpret_cast<const unsigned int*>(&accQ[m]);
        }
#pragma unroll
        for (int p = 0; p < 4; ++p) {
            sPc[row][4 * cg + p] = *reinterpret_cast<const unsigned int*>(&accC[p]);
        }
    }
    __syncthreads();

    // ---- Phase 3: vertical conv, 1 col x 4 rows per thread, f16 accum ----
    const int col = tid & 63;
    const int rbase = (tid >> 6) * 4;      // out rows rbase..rbase+3
    const unsigned int* pab = &sPab[rbase][col];
    const unsigned int* pq  = &sPq [rbase][col];
    const unsigned short* pc =
        reinterpret_cast<const unsigned short*>(&sPc[rbase][0]) + col;

    __half2 mAB[4], mQ[4], mC[2];
    {
        const __half2 z2 = __half2half2(hz);
#pragma unroll
        for (int r = 0; r < 4; ++r) { mAB[r] = z2; mQ[r] = z2; }
        mC[0] = z2; mC[1] = z2;
    }
#pragma unroll
    for (int j = 0; j < 14; ++j) {
        unsigned int uab = pab[j * 67];
        unsigned int uq  = pq [j * 67];
        unsigned short us = pc[j * 70];
        __half2 hab = *reinterpret_cast<const __half2*>(&uab);
        __half2 hq  = *reinterpret_cast<const __half2*>(&uq);
        __half2 hcs = __half2half2(__ushort_as_half(us));
#pragma unroll
        for (int r = 0; r < 4; ++r) {
            int i = j - r;
            if (i >= 0 && i <= 10) {
                mAB[r] = __hfma2(wsH[i], hab, mAB[r]);
                mQ[r]  = __hfma2(wsH[i], hq,  mQ[r]);
            }
        }
#pragma unroll
        for (int p = 0; p < 2; ++p) {
            int i = j - 2 * p;                 // rows (rbase+2p, rbase+2p+1)
            if (i >= 0 && i <= 11) mC[p] = __hfma2(wpH[i], hcs, mC[p]);
        }
    }

    float lsum = 0.f;
#pragma unroll
    for (int r = 0; r < 4; ++r) {
        float2 m12 = __half22float2(mAB[r]);
        float2 q2  = __half22float2(mQ[r]);
        float eab = __half2float((r & 1) ? __high2half(mC[r >> 1])
                                         : __low2half(mC[r >> 1]));
        float mu1 = m12.x, mu2 = m12.y;
        float mu11 = mu1 * mu1, mu22 = mu2 * mu2, mu12 = mu1 * mu2;
        float s1  = q2.x - mu11;
        float s2  = q2.y - mu22;
        float s12 = eab - mu12;
        float num = (2.f * mu12 + C1F) * (2.f * s12 + C2F);
        float den = (mu11 + mu22 + C1F) * (s1 + s2 + C2F);
        lsum += num * __builtin_amdgcn_rcpf(den);
    }

    // ---- Deterministic block reduction ----
#pragma unroll
    for (int off = 32; off > 0; off >>= 1) lsum += __shfl_down(lsum, off, 64);
    if ((tid & 63) == 0) wsum[tid >> 6] = lsum;
    __syncthreads();
    if (tid == 0) {
        float t = wsum[0] + wsum[1] + wsum[2] + wsum[3];
        partials[((size_t)blockIdx.z * GY + blockIdx.y) * GX + blockIdx.x] = t;
    }
}

__global__ __launch_bounds__(1024)
void ssim_reduce(const float* __restrict__ partials, float* __restrict__ out, int n) {
    __shared__ float lds[1024];
    float s = 0.f;
    for (int i = threadIdx.x; i < n; i += 1024) s += partials[i];
    lds[threadIdx.x] = s;
    __syncthreads();
    for (int off = 512; off > 0; off >>= 1) {
        if ((int)threadIdx.x < off) lds[threadIdx.x] += lds[threadIdx.x + off];
        __syncthreads();
    }
    if (threadIdx.x == 0) out[0] = 1.f - lds[0] / (float)NPIX;
}

extern "C" void kernel_launch(void* const* d_in, const int* in_sizes, int n_in,
                              void* d_out, int out_size, void* d_ws, size_t ws_size,
                              hipStream_t stream) {
    const float* img1 = (const float*)d_in[0];
    const float* img2 = (const float*)d_in[1];
    float* out = (float*)d_out;
    float* partials = (float*)d_ws;

    dim3 grid(GX, GY, GZ);
    ssim_tile<<<grid, 256, 0, stream>>>(img1, img2, partials);
    ssim_reduce<<<1, 1024, 0, stream>>>(partials, out, NBLOCKS);
}

// Round 6
// 61.169 us; speedup vs baseline: 1.7471x; 1.0934x over previous
//
#include <hip/hip_runtime.h>
#include <hip/hip_fp16.h>

// SSIM loss — round 6: TH=32 tile (halo amp 1.31), boundary fast-path loads,
// merged (ab,q) h-plane with ds_read_b64, P3 8 rows/thread.
// 256 threads, LDS ~27.7KB -> 5 blocks/CU.

#define IMGH 512
#define IMGW 512
#define TW 64
#define TH 32
#define HRR 42            // TH + 10 h-rows
#define C1F 1.0e-4f
#define C2F 9.0e-4f
#define GX 8
#define GY 16
#define GZ 48
#define NBLOCKS (GX * GY * GZ)   // 6144
#define NPIX (16 * 3 * 512 * 512)

// Gaussian weights, sigma=1.5, ws=11 (validated r1-r5).
#define W0 0.0010283818f
#define W1 0.0075987503f
#define W2 0.0360007547f
#define W3 0.1093606960f
#define W4 0.2130055367f
#define W5 0.2660117184f

struct alignas(8) H4 { __half2 ab; __half2 q; };   // (sa,sb) , (saa,sbb)

__global__ __launch_bounds__(256, 5)
void ssim_tile(const float* __restrict__ img1, const float* __restrict__ img2,
               float* __restrict__ partials) {
    // Merged h-plane: one b64 per (row,col). Row stride 65*8=520B (bank shift 2).
    __shared__ H4 sPm[HRR][65];             // 21,840 B
    __shared__ unsigned int sPc[HRR][35];   // ab f16, 2 cols/uint ; 5,880 B
    __shared__ float wsum[4];

    const float W[11] = {W0, W1, W2, W3, W4, W5, W4, W3, W2, W1, W0};
    const __half hz = __float2half(0.f);
    __half hWh[11];
#pragma unroll
    for (int i = 0; i < 11; ++i) hWh[i] = __float2half(W[i]);
    __half2 wsH[11];      // (W[i], W[i])
#pragma unroll
    for (int i = 0; i < 11; ++i) wsH[i] = __half2half2(hWh[i]);
    __half2 wpH[12];      // (W[i], W[i-1]), zero off-range
#pragma unroll
    for (int i = 0; i < 12; ++i)
        wpH[i] = __halves2half2(i <= 10 ? hWh[i] : hz, i >= 1 ? hWh[i - 1] : hz);

    const int tid = threadIdx.x;
    const int r0 = blockIdx.y * TH;
    const int c0 = blockIdx.x * TW;
    const size_t pbase = (size_t)blockIdx.z * (IMGH * IMGW);
    const float* a0 = img1 + pbase;
    const float* b0 = img2 + pbase;
    // Interior block: every load in-bounds (x in [1,6], y in [1,14]).
    const bool fast = (blockIdx.x >= 1) & (blockIdx.x <= GX - 2) &
                      (blockIdx.y >= 1) & (blockIdx.y <= GY - 2);

    // ---- Phase 2: horizontal conv, 8 out cols per item, 336 items ----
    auto h_item = [&](int idx) {
        const int row = idx >> 3;
        const int cg  = idx & 7;
        const int gr  = r0 - 5 + row;
        const bool rowok = (unsigned)gr < IMGH;
        const int grc = rowok ? gr : 0;
        const int gc0 = c0 + 8 * cg - 8;       // local col d <-> global gc0+d
        const float* ra = a0 + (size_t)grc * IMGW;
        const float* rb = b0 + (size_t)grc * IMGW;

        __half2 AB[18];
        float4 va, vb;
        auto cvt = [&](int g) {
            if (g == 0) { AB[0] = __floats2half2_rn(va.w, vb.w); return; }
            int t = 4 * g - 3;
            AB[t]     = __floats2half2_rn(va.x, vb.x);
            AB[t + 1] = __floats2half2_rn(va.y, vb.y);
            AB[t + 2] = __floats2half2_rn(va.z, vb.z);
            if (g < 5) AB[t + 3] = __floats2half2_rn(va.w, vb.w);
        };
        if (fast) {
#pragma unroll
            for (int g = 0; g < 6; ++g) {
                int gc = gc0 + 4 * g;
                va = *reinterpret_cast<const float4*>(ra + gc);
                vb = *reinterpret_cast<const float4*>(rb + gc);
                cvt(g);
            }
        } else {
#pragma unroll
            for (int g = 0; g < 6; ++g) {
                int gc = gc0 + 4 * g;
                va = make_float4(0.f, 0.f, 0.f, 0.f); vb = va;
                if (rowok && (unsigned)gc < IMGW) {
                    va = *reinterpret_cast<const float4*>(ra + gc);
                    vb = *reinterpret_cast<const float4*>(rb + gc);
                }
                cvt(g);
            }
        }

        __half2 accAB[8], accQ[8], accC[4];
        const __half2 z2 = __half2half2(hz);
#pragma unroll
        for (int m = 0; m < 8; ++m) { accAB[m] = z2; accQ[m] = z2; }
#pragma unroll
        for (int p = 0; p < 4; ++p) accC[p] = z2;
#pragma unroll
        for (int t = 0; t < 18; ++t) {
            __half2 ab = AB[t];
            __half2 q  = __hmul2(ab, ab);
            __half2 cs = __half2half2(__hmul(__low2half(ab), __high2half(ab)));
#pragma unroll
            for (int m = 0; m < 8; ++m) {
                int k = t - m;
                if (k >= 0 && k <= 10) {
                    accAB[m] = __hfma2(wsH[k], ab, accAB[m]);
                    accQ[m]  = __hfma2(wsH[k], q,  accQ[m]);
                }
            }
#pragma unroll
            for (int p = 0; p < 4; ++p) {
                int i = t - 2 * p;
                if (i >= 0 && i <= 11) accC[p] = __hfma2(wpH[i], cs, accC[p]);
            }
        }
#pragma unroll
        for (int m = 0; m < 8; ++m) {
            H4 h; h.ab = accAB[m]; h.q = accQ[m];
            sPm[row][8 * cg + m] = h;
        }
#pragma unroll
        for (int p = 0; p < 4; ++p)
            sPc[row][4 * cg + p] = *reinterpret_cast<const unsigned int*>(&accC[p]);
    };
    h_item(tid);
    if (tid < HRR * 8 - 256) h_item(tid + 256);   // 80 extra items
    __syncthreads();

    // ---- Phase 3: vertical conv, 1 col x 8 rows per thread ----
    const int col = tid & 63;
    const int rbase = (tid >> 6) * 8;      // out rows rbase..rbase+7
    const H4* pm = &sPm[rbase][col];
    const unsigned short* pc =
        reinterpret_cast<const unsigned short*>(&sPc[rbase][0]) + col;

    __half2 mAB[8], mQ[8], mC[4];
    {
        const __half2 z2 = __half2half2(hz);
#pragma unroll
        for (int r = 0; r < 8; ++r) { mAB[r] = z2; mQ[r] = z2; }
#pragma unroll
        for (int p = 0; p < 4; ++p) mC[p] = z2;
    }
#pragma unroll
    for (int j = 0; j < 18; ++j) {
        H4 h = pm[j * 65];
        unsigned short us = pc[j * 70];
        __half2 hcs = __half2half2(__ushort_as_half(us));
#pragma unroll
        for (int r = 0; r < 8; ++r) {
            int i = j - r;
            if (i >= 0 && i <= 10) {
                mAB[r] = __hfma2(wsH[i], h.ab, mAB[r]);
                mQ[r]  = __hfma2(wsH[i], h.q,  mQ[r]);
            }
        }
#pragma unroll
        for (int p = 0; p < 4; ++p) {
            int i = j - 2 * p;
            if (i >= 0 && i <= 11) mC[p] = __hfma2(wpH[i], hcs, mC[p]);
        }
    }

    float lsum = 0.f;
#pragma unroll
    for (int r = 0; r < 8; ++r) {
        float2 m12 = __half22float2(mAB[r]);
        float2 q2  = __half22float2(mQ[r]);
        float eab = __half2float((r & 1) ? __high2half(mC[r >> 1])
                                         : __low2half(mC[r >> 1]));
        float mu1 = m12.x, mu2 = m12.y;
        float mu11 = mu1 * mu1, mu22 = mu2 * mu2, mu12 = mu1 * mu2;
        float s1  = q2.x - mu11;
        float s2  = q2.y - mu22;
        float s12 = eab - mu12;
        float num = (2.f * mu12 + C1F) * (2.f * s12 + C2F);
        float den = (mu11 + mu22 + C1F) * (s1 + s2 + C2F);
        lsum += num * __builtin_amdgcn_rcpf(den);
    }

    // ---- Deterministic block reduction ----
#pragma unroll
    for (int off = 32; off > 0; off >>= 1) lsum += __shfl_down(lsum, off, 64);
    if ((tid & 63) == 0) wsum[tid >> 6] = lsum;
    __syncthreads();
    if (tid == 0) {
        float t = wsum[0] + wsum[1] + wsum[2] + wsum[3];
        partials[((size_t)blockIdx.z * GY + blockIdx.y) * GX + blockIdx.x] = t;
    }
}

__global__ __launch_bounds__(1024)
void ssim_reduce(const float* __restrict__ partials, float* __restrict__ out, int n) {
    __shared__ float lds[1024];
    float s = 0.f;
    for (int i = threadIdx.x; i < n; i += 1024) s += partials[i];
    lds[threadIdx.x] = s;
    __syncthreads();
    for (int off = 512; off > 0; off >>= 1) {
        if ((int)threadIdx.x < off) lds[threadIdx.x] += lds[threadIdx.x + off];
        __syncthreads();
    }
    if (threadIdx.x == 0) out[0] = 1.f - lds[0] / (float)NPIX;
}

extern "C" void kernel_launch(void* const* d_in, const int* in_sizes, int n_in,
                              void* d_out, int out_size, void* d_ws, size_t ws_size,
                              hipStream_t stream) {
    const float* img1 = (const float*)d_in[0];
    const float* img2 = (const float*)d_in[1];
    float* out = (float*)d_out;
    float* partials = (float*)d_ws;

    dim3 grid(GX, GY, GZ);
    ssim_tile<<<grid, 256, 0, stream>>>(img1, img2, partials);
    ssim_reduce<<<1, 1024, 0, stream>>>(partials, out, NBLOCKS);
}

// Round 8
// 55.115 us; speedup vs baseline: 1.9390x; 1.1098x over previous
//
#include <hip/hip_runtime.h>
#include <hip/hip_fp16.h>

// SSIM loss — round 8: r7 with pkrtz type fix (builtin returns __fp16 vec).
// Tile 64x32, 256 threads, LDS 26.1KB -> 6 blocks/CU. P2: h-conv direct from
// global (L3-resident), f16 packed math, merged (ab,q) b64 plane.
// P3: v-conv 8 rows/thread.

#define IMGH 512
#define IMGW 512
#define TW 64
#define TH 32
#define HRR 42            // TH + 10 h-rows
#define C1F 1.0e-4f
#define C2F 9.0e-4f
#define GX 8
#define GY 16
#define GZ 48
#define NBLOCKS (GX * GY * GZ)   // 6144
#define NPIX (16 * 3 * 512 * 512)

// Gaussian weights, sigma=1.5, ws=11 (validated r1-r6).
#define W0 0.0010283818f
#define W1 0.0075987503f
#define W2 0.0360007547f
#define W3 0.1093606960f
#define W4 0.2130055367f
#define W5 0.2660117184f

struct alignas(8) H4 { __half2 ab; __half2 q; };   // (sa,sb) , (saa,sbb)

static __device__ __forceinline__ __half2 pkrtz(float a, float b) {
    auto r = __builtin_amdgcn_cvt_pkrtz(a, b);   // __fp16 ext_vector(2)
    return *reinterpret_cast<__half2*>(&r);
}

__global__ __launch_bounds__(256, 6)
void ssim_tile(const float* __restrict__ img1, const float* __restrict__ img2,
               float* __restrict__ partials) {
    __shared__ H4 sPm[HRR][63];             // 21,168 B
    __shared__ unsigned int sPc[HRR][33];   // ab f16, 2 cols/uint ; 5,544 B
    __shared__ float wsum[4];

    const float W[11] = {W0, W1, W2, W3, W4, W5, W4, W3, W2, W1, W0};
    const __half hz = __float2half(0.f);
    __half hWh[11];
#pragma unroll
    for (int i = 0; i < 11; ++i) hWh[i] = __float2half(W[i]);
    __half2 wsH[11];      // (W[i], W[i])
#pragma unroll
    for (int i = 0; i < 11; ++i) wsH[i] = __half2half2(hWh[i]);
    __half2 wpH[12];      // (W[i], W[i-1]), zero off-range
#pragma unroll
    for (int i = 0; i < 12; ++i)
        wpH[i] = __halves2half2(i <= 10 ? hWh[i] : hz, i >= 1 ? hWh[i - 1] : hz);

    const int tid = threadIdx.x;
    const int r0 = blockIdx.y * TH;
    const int c0 = blockIdx.x * TW;
    const size_t pbase = (size_t)blockIdx.z * (IMGH * IMGW);
    const float* a0 = img1 + pbase;
    const float* b0 = img2 + pbase;
    const bool fast = (blockIdx.x >= 1) & (blockIdx.x <= GX - 2) &
                      (blockIdx.y >= 1) & (blockIdx.y <= GY - 2);

    // ---- Phase 2: horizontal conv, 8 out cols per item, 336 items ----
    auto h_item = [&](int idx) {
        const int row = idx >> 3;
        const int cg  = idx & 7;
        const int gr  = r0 - 5 + row;
        const bool rowok = (unsigned)gr < IMGH;
        const int grc = rowok ? gr : 0;
        const int gc0 = c0 + 8 * cg - 8;       // local col d <-> global gc0+d
        const float* ra = a0 + (size_t)grc * IMGW;
        const float* rb = b0 + (size_t)grc * IMGW;

        __half2 AB[18];
        float4 va, vb;
        auto cvt = [&](int g) {
            if (g == 0) { AB[0] = pkrtz(va.w, vb.w); return; }
            int t = 4 * g - 3;
            AB[t]     = pkrtz(va.x, vb.x);
            AB[t + 1] = pkrtz(va.y, vb.y);
            AB[t + 2] = pkrtz(va.z, vb.z);
            if (g < 5) AB[t + 3] = pkrtz(va.w, vb.w);
        };
        if (fast) {
#pragma unroll
            for (int g = 0; g < 6; ++g) {
                int gc = gc0 + 4 * g;
                va = *reinterpret_cast<const float4*>(ra + gc);
                vb = *reinterpret_cast<const float4*>(rb + gc);
                cvt(g);
            }
        } else {
#pragma unroll
            for (int g = 0; g < 6; ++g) {
                int gc = gc0 + 4 * g;
                va = make_float4(0.f, 0.f, 0.f, 0.f); vb = va;
                if (rowok && (unsigned)gc < IMGW) {
                    va = *reinterpret_cast<const float4*>(ra + gc);
                    vb = *reinterpret_cast<const float4*>(rb + gc);
                }
                cvt(g);
            }
        }

        __half2 accAB[8], accQ[8], accC[4];
        const __half2 z2 = __half2half2(hz);
#pragma unroll
        for (int m = 0; m < 8; ++m) { accAB[m] = z2; accQ[m] = z2; }
#pragma unroll
        for (int p = 0; p < 4; ++p) accC[p] = z2;
#pragma unroll
        for (int t = 0; t < 18; ++t) {
            __half2 ab = AB[t];
            __half2 q  = __hmul2(ab, ab);
            __half2 cs = __half2half2(__hmul(__low2half(ab), __high2half(ab)));
#pragma unroll
            for (int m = 0; m < 8; ++m) {
                int k = t - m;
                if (k >= 0 && k <= 10) {
                    accAB[m] = __hfma2(wsH[k], ab, accAB[m]);
                    accQ[m]  = __hfma2(wsH[k], q,  accQ[m]);
                }
            }
#pragma unroll
            for (int p = 0; p < 4; ++p) {
                int i = t - 2 * p;
                if (i >= 0 && i <= 11) accC[p] = __hfma2(wpH[i], cs, accC[p]);
            }
        }
#pragma unroll
        for (int m = 0; m < 8; ++m) {
            H4 h; h.ab = accAB[m]; h.q = accQ[m];
            sPm[row][8 * cg + m] = h;
        }
#pragma unroll
        for (int p = 0; p < 4; ++p)
            sPc[row][4 * cg + p] = *reinterpret_cast<const unsigned int*>(&accC[p]);
    };
    h_item(tid);
    if (tid < HRR * 8 - 256) h_item(tid + 256);   // 80 extra items
    __syncthreads();

    // ---- Phase 3: vertical conv, 1 col x 8 rows per thread ----
    const int col = tid & 63;
    const int rbase = (tid >> 6) * 8;      // out rows rbase..rbase+7
    const H4* pm = &sPm[rbase][col];
    const unsigned short* pc =
        reinterpret_cast<const unsigned short*>(&sPc[rbase][0]) + col;

    __half2 mAB[8], mQ[8], mC[4];
    {
        const __half2 z2 = __half2half2(hz);
#pragma unroll
        for (int r = 0; r < 8; ++r) { mAB[r] = z2; mQ[r] = z2; }
#pragma unroll
        for (int p = 0; p < 4; ++p) mC[p] = z2;
    }
#pragma unroll
    for (int j = 0; j < 18; ++j) {
        H4 h = pm[j * 63];
        unsigned short us = pc[j * 66];
        __half2 hcs = __half2half2(__ushort_as_half(us));
#pragma unroll
        for (int r = 0; r < 8; ++r) {
            int i = j - r;
            if (i >= 0 && i <= 10) {
                mAB[r] = __hfma2(wsH[i], h.ab, mAB[r]);
                mQ[r]  = __hfma2(wsH[i], h.q,  mQ[r]);
            }
        }
#pragma unroll
        for (int p = 0; p < 4; ++p) {
            int i = j - 2 * p;
            if (i >= 0 && i <= 11) mC[p] = __hfma2(wpH[i], hcs, mC[p]);
        }
    }

    float lsum = 0.f;
#pragma unroll
    for (int r = 0; r < 8; ++r) {
        float2 m12 = __half22float2(mAB[r]);
        float2 q2  = __half22float2(mQ[r]);
        float eab = __half2float((r & 1) ? __high2half(mC[r >> 1])
                                         : __low2half(mC[r >> 1]));
        float mu1 = m12.x, mu2 = m12.y;
        float mu11 = mu1 * mu1, mu22 = mu2 * mu2, mu12 = mu1 * mu2;
        float s1  = q2.x - mu11;
        float s2  = q2.y - mu22;
        float s12 = eab - mu12;
        float num = (2.f * mu12 + C1F) * (2.f * s12 + C2F);
        float den = (mu11 + mu22 + C1F) * (s1 + s2 + C2F);
        lsum += num * __builtin_amdgcn_rcpf(den);
    }

    // ---- Deterministic block reduction ----
#pragma unroll
    for (int off = 32; off > 0; off >>= 1) lsum += __shfl_down(lsum, off, 64);
    if ((tid & 63) == 0) wsum[tid >> 6] = lsum;
    __syncthreads();
    if (tid == 0) {
        float t = wsum[0] + wsum[1] + wsum[2] + wsum[3];
        partials[((size_t)blockIdx.z * GY + blockIdx.y) * GX + blockIdx.x] = t;
    }
}

__global__ __launch_bounds__(1024)
void ssim_reduce(const float* __restrict__ partials, float* __restrict__ out, int n) {
    __shared__ float lds[1024];
    float s = 0.f;
    for (int i = threadIdx.x; i < n; i += 1024) s += partials[i];
    lds[threadIdx.x] = s;
    __syncthreads();
    for (int off = 512; off > 0; off >>= 1) {
        if ((int)threadIdx.x < off) lds[threadIdx.x] += lds[threadIdx.x + off];
        __syncthreads();
    }
    if (threadIdx.x == 0) out[0] = 1.f - lds[0] / (float)NPIX;
}

extern "C" void kernel_launch(void* const* d_in, const int* in_sizes, int n_in,
                              void* d_out, int out_size, void* d_ws, size_t ws_size,
                              hipStream_t stream) {
    const float* img1 = (const float*)d_in[0];
    const float* img2 = (const float*)d_in[1];
    float* out = (float*)d_out;
    float* partials = (float*)d_ws;

    dim3 grid(GX, GY, GZ);
    ssim_tile<<<grid, 256, 0, stream>>>(img1, img2, partials);
    ssim_reduce<<<1, 1024, 0, stream>>>(partials, out, NBLOCKS);
}

// Round 9
// 50.919 us; speedup vs baseline: 2.0988x; 1.0824x over previous
//
#include <hip/hip_runtime.h>
#include <hip/hip_fp16.h>

// SSIM loss — round 9: merged 4-half h-plane {(sa,sb),(qsum=saa+sbb, sab)}.
// Key identity: SSIM needs only (E[aa]+E[bb]), never separately -> fold at
// h-pass, halving plane bytes. LDS 21.2KB -> 7 blocks/CU.
// Tile 64x32, 256 threads. P2 direct-from-global (L3-resident), f16 packed.
// P3: one ds_read_b64 per (j), 16 hfma2 per j, 8 rows/thread.

#define IMGH 512
#define IMGW 512
#define TW 64
#define TH 32
#define HRR 42            // TH + 10 h-rows
#define C1F 1.0e-4f
#define C2F 9.0e-4f
#define GX 8
#define GY 16
#define GZ 48
#define NBLOCKS (GX * GY * GZ)   // 6144
#define NPIX (16 * 3 * 512 * 512)

// Gaussian weights, sigma=1.5, ws=11 (validated r1-r8).
#define W0 0.0010283818f
#define W1 0.0075987503f
#define W2 0.0360007547f
#define W3 0.1093606960f
#define W4 0.2130055367f
#define W5 0.2660117184f

struct alignas(8) H4 { __half2 ab; __half2 qc; };  // (sa,sb) , (saa+sbb, sab)

static __device__ __forceinline__ __half2 pkrtz(float a, float b) {
    auto r = __builtin_amdgcn_cvt_pkrtz(a, b);   // __fp16 ext_vector(2)
    return *reinterpret_cast<__half2*>(&r);
}

__global__ __launch_bounds__(256, 7)
void ssim_tile(const float* __restrict__ img1, const float* __restrict__ img2,
               float* __restrict__ partials) {
    __shared__ H4 sPm[HRR][63];             // 21,168 B
    __shared__ float wsum[4];

    const float W[11] = {W0, W1, W2, W3, W4, W5, W4, W3, W2, W1, W0};
    const __half hz = __float2half(0.f);
    __half2 wsH[11];      // (W[i], W[i])
#pragma unroll
    for (int i = 0; i < 11; ++i) wsH[i] = __half2half2(__float2half(W[i]));

    const int tid = threadIdx.x;
    const int r0 = blockIdx.y * TH;
    const int c0 = blockIdx.x * TW;
    const size_t pbase = (size_t)blockIdx.z * (IMGH * IMGW);
    const float* a0 = img1 + pbase;
    const float* b0 = img2 + pbase;
    const bool fast = (blockIdx.x >= 1) & (blockIdx.x <= GX - 2) &
                      (blockIdx.y >= 1) & (blockIdx.y <= GY - 2);

    // ---- Phase 2: horizontal conv, 8 out cols per item, 336 items ----
    auto h_item = [&](int idx) {
        const int row = idx >> 3;
        const int cg  = idx & 7;
        const int gr  = r0 - 5 + row;
        const bool rowok = (unsigned)gr < IMGH;
        const int grc = rowok ? gr : 0;
        const int gc0 = c0 + 8 * cg - 8;       // local col d <-> global gc0+d
        const float* ra = a0 + (size_t)grc * IMGW;
        const float* rb = b0 + (size_t)grc * IMGW;

        __half2 AB[18];
        float4 va, vb;
        auto cvt = [&](int g) {
            if (g == 0) { AB[0] = pkrtz(va.w, vb.w); return; }
            int t = 4 * g - 3;
            AB[t]     = pkrtz(va.x, vb.x);
            AB[t + 1] = pkrtz(va.y, vb.y);
            AB[t + 2] = pkrtz(va.z, vb.z);
            if (g < 5) AB[t + 3] = pkrtz(va.w, vb.w);
        };
        if (fast) {
#pragma unroll
            for (int g = 0; g < 6; ++g) {
                int gc = gc0 + 4 * g;
                va = *reinterpret_cast<const float4*>(ra + gc);
                vb = *reinterpret_cast<const float4*>(rb + gc);
                cvt(g);
            }
        } else {
#pragma unroll
            for (int g = 0; g < 6; ++g) {
                int gc = gc0 + 4 * g;
                va = make_float4(0.f, 0.f, 0.f, 0.f); vb = va;
                if (rowok && (unsigned)gc < IMGW) {
                    va = *reinterpret_cast<const float4*>(ra + gc);
                    vb = *reinterpret_cast<const float4*>(rb + gc);
                }
                cvt(g);
            }
        }

        __half2 accAB[8], accQC[8];
        const __half2 z2 = __half2half2(hz);
#pragma unroll
        for (int m = 0; m < 8; ++m) { accAB[m] = z2; accQC[m] = z2; }
#pragma unroll
        for (int t = 0; t < 18; ++t) {
            __half2 ab = AB[t];
            __half2 q2 = __hmul2(ab, ab);                       // (aa, bb)
            __half a_ = __low2half(ab), b_ = __high2half(ab);
            __half2 qc = __halves2half2(
                __hadd(__low2half(q2), __high2half(q2)),        // aa+bb
                __hmul(a_, b_));                                // ab
#pragma unroll
            for (int m = 0; m < 8; ++m) {
                int k = t - m;
                if (k >= 0 && k <= 10) {
                    accAB[m] = __hfma2(wsH[k], ab, accAB[m]);
                    accQC[m] = __hfma2(wsH[k], qc, accQC[m]);
                }
            }
        }
#pragma unroll
        for (int m = 0; m < 8; ++m) {
            H4 h; h.ab = accAB[m]; h.qc = accQC[m];
            sPm[row][8 * cg + m] = h;
        }
    };
    h_item(tid);
    if (tid < HRR * 8 - 256) h_item(tid + 256);   // 80 extra items
    __syncthreads();

    // ---- Phase 3: vertical conv, 1 col x 8 rows per thread ----
    const int col = tid & 63;
    const int rbase = (tid >> 6) * 8;      // out rows rbase..rbase+7
    const H4* pm = &sPm[rbase][col];

    __half2 mAB[8], mQC[8];
    {
        const __half2 z2 = __half2half2(hz);
#pragma unroll
        for (int r = 0; r < 8; ++r) { mAB[r] = z2; mQC[r] = z2; }
    }
#pragma unroll
    for (int j = 0; j < 18; ++j) {
        H4 h = pm[j * 63];
#pragma unroll
        for (int r = 0; r < 8; ++r) {
            int i = j - r;
            if (i >= 0 && i <= 10) {
                mAB[r] = __hfma2(wsH[i], h.ab, mAB[r]);
                mQC[r] = __hfma2(wsH[i], h.qc, mQC[r]);
            }
        }
    }

    float lsum = 0.f;
#pragma unroll
    for (int r = 0; r < 8; ++r) {
        float2 m12 = __half22float2(mAB[r]);
        float2 qc  = __half22float2(mQC[r]);   // (E[aa]+E[bb], E[ab])
        float mu1 = m12.x, mu2 = m12.y;
        float mu11 = mu1 * mu1, mu22 = mu2 * mu2, mu12 = mu1 * mu2;
        float s12 = qc.y - mu12;
        float num = (2.f * mu12 + C1F) * (2.f * s12 + C2F);
        float den = (mu11 + mu22 + C1F) * ((qc.x - mu11 - mu22) + C2F);
        lsum += num * __builtin_amdgcn_rcpf(den);
    }

    // ---- Deterministic block reduction ----
#pragma unroll
    for (int off = 32; off > 0; off >>= 1) lsum += __shfl_down(lsum, off, 64);
    if ((tid & 63) == 0) wsum[tid >> 6] = lsum;
    __syncthreads();
    if (tid == 0) {
        float t = wsum[0] + wsum[1] + wsum[2] + wsum[3];
        partials[((size_t)blockIdx.z * GY + blockIdx.y) * GX + blockIdx.x] = t;
    }
}

__global__ __launch_bounds__(1024)
void ssim_reduce(const float* __restrict__ partials, float* __restrict__ out, int n) {
    __shared__ float lds[1024];
    float s = 0.f;
    for (int i = threadIdx.x; i < n; i += 1024) s += partials[i];
    lds[threadIdx.x] = s;
    __syncthreads();
    for (int off = 512; off > 0; off >>= 1) {
        if ((int)threadIdx.x < off) lds[threadIdx.x] += lds[threadIdx.x + off];
        __syncthreads();
    }
    if (threadIdx.x == 0) out[0] = 1.f - lds[0] / (float)NPIX;
}

extern "C" void kernel_launch(void* const* d_in, const int* in_sizes, int n_in,
                              void* d_out, int out_size, void* d_ws, size_t ws_size,
                              hipStream_t stream) {
    const float* img1 = (const float*)d_in[0];
    const float* img2 = (const float*)d_in[1];
    float* out = (float*)d_out;
    float* partials = (float*)d_ws;

    dim3 grid(GX, GY, GZ);
    ssim_tile<<<grid, 256, 0, stream>>>(img1, img2, partials);
    ssim_reduce<<<1, 1024, 0, stream>>>(partials, out, NBLOCKS);
}

// Round 10
// 46.512 us; speedup vs baseline: 2.2976x; 1.0947x over previous
//
#include <hip/hip_runtime.h>
#include <hip/hip_fp16.h>

// SSIM loss — round 10.
// Fixes r9 latent OOB (plane stride 63 -> 64; col 63 aliased next row).
// Plane stride 64 H4 = 512B/row -> P3 reads use constant imm offsets.
// P2: qc=(aa+bb, ab) built in f32 during the load shadow; hot loop is pure
// 176 hfma2 over AB[]/QC[]. P3: all 18 ds_read_b64 hoisted, then pure math.
// Tile 64x32, 256 threads, LDS 22.0KB -> 7 blocks/CU.

#define IMGH 512
#define IMGW 512
#define TW 64
#define TH 32
#define HRR 42            // TH + 10 h-rows
#define C1F 1.0e-4f
#define C2F 9.0e-4f
#define GX 8
#define GY 16
#define GZ 48
#define NBLOCKS (GX * GY * GZ)   // 6144
#define NPIX (16 * 3 * 512 * 512)

// Gaussian weights, sigma=1.5, ws=11 (validated r1-r9).
#define W0 0.0010283818f
#define W1 0.0075987503f
#define W2 0.0360007547f
#define W3 0.1093606960f
#define W4 0.2130055367f
#define W5 0.2660117184f

struct alignas(8) H4 { __half2 ab; __half2 qc; };  // (sa,sb) , (saa+sbb, sab)

static __device__ __forceinline__ __half2 pkrtz(float a, float b) {
    auto r = __builtin_amdgcn_cvt_pkrtz(a, b);   // __fp16 ext_vector(2)
    return *reinterpret_cast<__half2*>(&r);
}

__global__ __launch_bounds__(256, 7)
void ssim_tile(const float* __restrict__ img1, const float* __restrict__ img2,
               float* __restrict__ partials) {
    __shared__ H4 sPm[HRR][64];             // 21,504 B, stride 512B
    __shared__ float wsum[4];

    const float W[11] = {W0, W1, W2, W3, W4, W5, W4, W3, W2, W1, W0};
    __half2 wsH[11];      // (W[i], W[i])
#pragma unroll
    for (int i = 0; i < 11; ++i) wsH[i] = __half2half2(__float2half(W[i]));

    const int tid = threadIdx.x;
    const int r0 = blockIdx.y * TH;
    const int c0 = blockIdx.x * TW;
    const size_t pbase = (size_t)blockIdx.z * (IMGH * IMGW);
    const float* a0 = img1 + pbase;
    const float* b0 = img2 + pbase;
    const bool fast = (blockIdx.x >= 1) & (blockIdx.x <= GX - 2) &
                      (blockIdx.y >= 1) & (blockIdx.y <= GY - 2);

    // ---- Phase 2: horizontal conv, 8 out cols per item, 336 items ----
    auto h_item = [&](int idx) {
        const int row = idx >> 3;
        const int cg  = idx & 7;
        const int gr  = r0 - 5 + row;
        const bool rowok = (unsigned)gr < IMGH;
        const int grc = rowok ? gr : 0;
        const int gc0 = c0 + 8 * cg - 8;       // local col d <-> global gc0+d
        const float* ra = a0 + (size_t)grc * IMGW;
        const float* rb = b0 + (size_t)grc * IMGW;

        __half2 AB[18], QC[18];
        float4 va, vb;
        auto emit = [&](int t, float a, float b) {
            AB[t] = pkrtz(a, b);
            QC[t] = pkrtz(__builtin_fmaf(a, a, b * b), a * b);
        };
        auto cvt = [&](int g) {
            if (g == 0) { emit(0, va.w, vb.w); return; }
            int t = 4 * g - 3;
            emit(t,     va.x, vb.x);
            emit(t + 1, va.y, vb.y);
            emit(t + 2, va.z, vb.z);
            if (g < 5) emit(t + 3, va.w, vb.w);
        };
        if (fast) {
#pragma unroll
            for (int g = 0; g < 6; ++g) {
                int gc = gc0 + 4 * g;
                va = *reinterpret_cast<const float4*>(ra + gc);
                vb = *reinterpret_cast<const float4*>(rb + gc);
                cvt(g);
            }
        } else {
#pragma unroll
            for (int g = 0; g < 6; ++g) {
                int gc = gc0 + 4 * g;
                va = make_float4(0.f, 0.f, 0.f, 0.f); vb = va;
                if (rowok && (unsigned)gc < IMGW) {
                    va = *reinterpret_cast<const float4*>(ra + gc);
                    vb = *reinterpret_cast<const float4*>(rb + gc);
                }
                cvt(g);
            }
        }

        __half2 accAB[8], accQC[8];
        const __half2 z2 = __half2half2(__float2half(0.f));
#pragma unroll
        for (int m = 0; m < 8; ++m) { accAB[m] = z2; accQC[m] = z2; }
#pragma unroll
        for (int t = 0; t < 18; ++t) {
#pragma unroll
            for (int m = 0; m < 8; ++m) {
                int k = t - m;
                if (k >= 0 && k <= 10) {
                    accAB[m] = __hfma2(wsH[k], AB[t], accAB[m]);
                    accQC[m] = __hfma2(wsH[k], QC[t], accQC[m]);
                }
            }
        }
#pragma unroll
        for (int m = 0; m < 8; ++m) {
            H4 h; h.ab = accAB[m]; h.qc = accQC[m];
            sPm[row][8 * cg + m] = h;
        }
    };
    h_item(tid);
    if (tid < HRR * 8 - 256) h_item(tid + 256);   // 80 extra items
    __syncthreads();

    // ---- Phase 3: vertical conv, 1 col x 8 rows per thread ----
    const int col = tid & 63;
    const int rbase = (tid >> 6) * 8;      // out rows rbase..rbase+7
    const H4* pm = &sPm[rbase][col];

    H4 hbuf[18];
#pragma unroll
    for (int j = 0; j < 18; ++j) hbuf[j] = pm[j * 64];   // imm offset j*512B

    __half2 mAB[8], mQC[8];
    {
        const __half2 z2 = __half2half2(__float2half(0.f));
#pragma unroll
        for (int r = 0; r < 8; ++r) { mAB[r] = z2; mQC[r] = z2; }
    }
#pragma unroll
    for (int j = 0; j < 18; ++j) {
#pragma unroll
        for (int r = 0; r < 8; ++r) {
            int i = j - r;
            if (i >= 0 && i <= 10) {
                mAB[r] = __hfma2(wsH[i], hbuf[j].ab, mAB[r]);
                mQC[r] = __hfma2(wsH[i], hbuf[j].qc, mQC[r]);
            }
        }
    }

    float lsum = 0.f;
#pragma unroll
    for (int r = 0; r < 8; ++r) {
        float2 m12 = __half22float2(mAB[r]);
        float2 qc  = __half22float2(mQC[r]);   // (E[aa]+E[bb], E[ab])
        float mu1 = m12.x, mu2 = m12.y;
        float mu11 = mu1 * mu1, mu22 = mu2 * mu2, mu12 = mu1 * mu2;
        float s12 = qc.y - mu12;
        float num = (2.f * mu12 + C1F) * (2.f * s12 + C2F);
        float den = (mu11 + mu22 + C1F) * ((qc.x - mu11 - mu22) + C2F);
        lsum += num * __builtin_amdgcn_rcpf(den);
    }

    // ---- Deterministic block reduction ----
#pragma unroll
    for (int off = 32; off > 0; off >>= 1) lsum += __shfl_down(lsum, off, 64);
    if ((tid & 63) == 0) wsum[tid >> 6] = lsum;
    __syncthreads();
    if (tid == 0) {
        float t = wsum[0] + wsum[1] + wsum[2] + wsum[3];
        partials[((size_t)blockIdx.z * GY + blockIdx.y) * GX + blockIdx.x] = t;
    }
}

__global__ __launch_bounds__(1024)
void ssim_reduce(const float* __restrict__ partials, float* __restrict__ out, int n) {
    __shared__ float lds[1024];
    float s = 0.f;
    for (int i = threadIdx.x; i < n; i += 1024) s += partials[i];
    lds[threadIdx.x] = s;
    __syncthreads();
    for (int off = 512; off > 0; off >>= 1) {
        if ((int)threadIdx.x < off) lds[threadIdx.x] += lds[threadIdx.x + off];
        __syncthreads();
    }
    if (threadIdx.x == 0) out[0] = 1.f - lds[0] / (float)NPIX;
}

extern "C" void kernel_launch(void* const* d_in, const int* in_sizes, int n_in,
                              void* d_out, int out_size, void* d_ws, size_t ws_size,
                              hipStream_t stream) {
    const float* img1 = (const float*)d_in[0];
    const float* img2 = (const float*)d_in[1];
    float* out = (float*)d_out;
    float* partials = (float*)d_ws;

    dim3 grid(GX, GY, GZ);
    ssim_tile<<<grid, 256, 0, stream>>>(img1, img2, partials);
    ssim_reduce<<<1, 1024, 0, stream>>>(partials, out, NBLOCKS);
}